// Round 14
// baseline (436.927 us; speedup 1.0000x reference)
//
#include <hip/hip_runtime.h>
#include <float.h>

#define NTOK 32768  // 16 * 2048 tokens per modality

typedef __attribute__((ext_vector_type(8))) short bf16x8;
typedef __attribute__((ext_vector_type(4))) float f32x4;

// ---- ws byte layout ----
#define WSB_W2    0          // 1280 floats
#define WSB_X2    8192       // 5*NTOK floats
#define WSB_CNT   663808     // 5 ints
#define WSB_LIST  664064     // 5*NTOK ints
#define WSB_WSP   1572864    // packed bf16-hi A-fragment slabs
#define WSB_KEY   2424832    // 5*NTOK u64 argmin keys

struct AllPtrs {
    const float* X[5];
    const float* W[5];
    unsigned char* Wsp[5];
    float* w2[5];
    float* q[5];
    float* idx[5];
    float* x2[5];
    int* cnt;
    int* lst;                  // + m*NTOK
    unsigned long long* keys;  // + m*NTOK
    float* loss;
};

__device__ __forceinline__ unsigned short f2bf(float f) {
    unsigned u = __float_as_uint(f);
    return (unsigned short)((u + 0x7FFFu + ((u >> 16) & 1u)) >> 16);
}
__device__ __forceinline__ float bf2f(unsigned short h) {
    return __uint_as_float(((unsigned)h) << 16);
}

// ============ numpy pairwise-sum replica (fp32, PW_BLOCKSIZE=128) ===========
__device__ __forceinline__ float pw_sq_block_g(const float* __restrict__ a, int n) {
    float r[8];
    #pragma unroll
    for (int j = 0; j < 8; ++j) r[j] = __fmul_rn(a[j], a[j]);
    for (int i = 8; i < n; i += 8)
        #pragma unroll
        for (int j = 0; j < 8; ++j)
            r[j] = __fadd_rn(r[j], __fmul_rn(a[i + j], a[i + j]));
    return __fadd_rn(__fadd_rn(__fadd_rn(r[0], r[1]), __fadd_rn(r[2], r[3])),
                     __fadd_rn(__fadd_rn(r[4], r[5]), __fadd_rn(r[6], r[7])));
}

template <int D>
__device__ __forceinline__ void w2_body(const float* __restrict__ W,
                                        float* __restrict__ w2, int k, int K) {
    if (k >= K) return;
    const float* row = W + (size_t)k * D;
    float s = (D > 128)
        ? __fadd_rn(pw_sq_block_g(row, 128), pw_sq_block_g(row + 128, D - 128))
        : pw_sq_block_g(row, D);
    w2[k] = s;
}

// ---- pack W-hi plane as per-lane A-fragment slabs -------------------------
// slab(tile, ds) = 1KB contiguous: lane l holds bytes [l*16, l*16+16) =
// codes row=l&15, k-octet kg=l>>4 -> element (k = tile*16+row? no: row within
// tile; d = ds*32 + kg*8 + e). Read side: one contiguous 1KB per wave-load.
template <int D, int K>
__device__ __forceinline__ void wsplit_body(const float* __restrict__ W,
                                            unsigned char* __restrict__ dst, int i) {
    if (i >= K * D / 2) return;
    int k  = i / (D / 2);
    int d2 = i % (D / 2);
    int d  = 2 * d2;
    float2 v = *(const float2*)(W + (size_t)k * D + d);
    unsigned short h0 = f2bf(v.x), h1 = f2bf(v.y);
    int tile = k >> 4, row = k & 15;
    int ds = d >> 5, kg = (d >> 3) & 3, e = d & 7;
    int lane = row | (kg << 4);
    size_t off = (size_t)tile * (D * 32) + ds * 1024 + lane * 16 + e * 2;
    *(unsigned int*)(dst + off) = (unsigned)h0 | ((unsigned)h1 << 16);
}

// ---- prep: zero loss/cnt, w2 (np-replica), W packed hi-plane --------------
__global__ __launch_bounds__(256) void prep_mega(AllPtrs P) {
    const int bid = blockIdx.x, tid = threadIdx.x;
    if (bid == 0 && tid == 0) *P.loss = 0.f;
    if (bid == 0 && tid < 5) P.cnt[tid] = 0;
    if (bid < 6) {
        if (bid < 2)      w2_body<256>(P.W[0], P.w2[0], bid * 256 + tid, 512);
        else if (bid == 2) w2_body<128>(P.W[1], P.w2[1], tid, 256);
        else if (bid == 3) w2_body<64> (P.W[2], P.w2[2], tid, 128);
        else if (bid == 4) w2_body<128>(P.W[3], P.w2[3], tid, 256);
        else               w2_body<64> (P.W[4], P.w2[4], tid, 128);
    } else {
        int b = bid - 6;
        if (b < 256)      wsplit_body<256, 512>(P.W[0], P.Wsp[0], b * 256 + tid);
        else if (b < 320) wsplit_body<128, 256>(P.W[1], P.Wsp[1], (b - 256) * 256 + tid);
        else if (b < 336) wsplit_body<64, 128> (P.W[2], P.Wsp[2], (b - 320) * 256 + tid);
        else if (b < 400) wsplit_body<128, 256>(P.W[3], P.Wsp[3], (b - 336) * 256 + tid);
        else              wsplit_body<64, 128> (P.W[4], P.Wsp[4], (b - 400) * 256 + tid);
    }
}

// ---- numpy-pairwise ||x||^2 replica, wave-cooperative (all lanes get it) ---
template <int D>
__device__ __forceinline__ float x2_replica(const float* __restrict__ xr, int lane) {
    const int jg = (lane >> 4) & 3;
    constexpr int B1M = (D > 128) ? 16 : (D / 8);
    float2 v = *(const float2*)(xr + 2 * jg);
    float r0 = __fmul_rn(v.x, v.x), r1 = __fmul_rn(v.y, v.y);
    #pragma unroll
    for (int m = 1; m < B1M; ++m) {
        float2 u = *(const float2*)(xr + 8 * m + 2 * jg);
        r0 = __fadd_rn(r0, __fmul_rn(u.x, u.x));
        r1 = __fadd_rn(r1, __fmul_rn(u.y, u.y));
    }
    float p = __fadd_rn(r0, r1);
    p = __fadd_rn(p, __shfl_xor(p, 16, 64));
    p = __fadd_rn(p, __shfl_xor(p, 32, 64));
    if (D > 128) {
        float2 w0 = *(const float2*)(xr + 128 + 2 * jg);
        float s0 = __fmul_rn(w0.x, w0.x), s1 = __fmul_rn(w0.y, w0.y);
        #pragma unroll
        for (int m = 1; m < 16; ++m) {
            float2 u = *(const float2*)(xr + 128 + 8 * m + 2 * jg);
            s0 = __fadd_rn(s0, __fmul_rn(u.x, u.x));
            s1 = __fadd_rn(s1, __fmul_rn(u.y, u.y));
        }
        float q2 = __fadd_rn(s0, s1);
        q2 = __fadd_rn(q2, __shfl_xor(q2, 16, 64));
        q2 = __fadd_rn(q2, __shfl_xor(q2, 32, 64));
        p = __fadd_rn(p, q2);
    }
    return p;
}

// ---- MFMA screen body: A-frags streamed from L2, no LDS, no k-loop barriers
template <int D, int K, int M>
__device__ void vq_body(const AllPtrs& P, int tile, int* idx_s)
{
    constexpr int DS    = D / 32;       // k-steps per code tile
    constexpr int NT    = K / 16;       // 16-code tiles
    constexpr int TILEB = D * 32;       // bytes per tile (hi plane only)
    const float inv_nd = 1.0f / (32768.0f * (float)D);
    // screen-error margin: np-quant + 8-sigma of x.wl (W-lo dropped) + eps
    const float mc = 0.018f / (float)K; // 8 * 2*2^-9/sqrt(3) / K

    const float* X   = P.X[M];
    const float* W   = P.W[M];
    const unsigned char* Wsp = P.Wsp[M];
    const float* w2  = P.w2[M];
    float* q_out     = P.q[M];
    float* idx_out   = P.idx[M];
    float* x2_save   = P.x2[M];
    int*   cnt_m     = P.cnt + M;
    int*   lst_m     = P.lst + M * NTOK;
    unsigned long long* keys_m = P.keys + M * NTOK;

    const int tid  = threadIdx.x;
    const int lane = tid & 63;
    const int wv   = tid >> 6;
    const int t0   = tile * 64;
    const int tw   = t0 + wv * 16 + (lane & 15);

    // phase 0: np-replica ||x||^2
    const float x2v = x2_replica<D>(X + (size_t)tw * D, lane);
    if ((lane >> 4) == 0) x2_save[tw] = x2v;

    // phase 1: X B-fragments (bf16 hi/lo) in registers
    bf16x8 bhi[DS], blo[DS];
    {
        const float* xr = X + (size_t)tw * D + ((lane >> 4) & 3) * 8;
        #pragma unroll
        for (int ds = 0; ds < DS; ++ds) {
            float4 a = *(const float4*)(xr + ds * 32);
            float4 b = *(const float4*)(xr + ds * 32 + 4);
            float f[8] = {a.x, a.y, a.z, a.w, b.x, b.y, b.z, b.w};
            bf16x8 h, l;
            #pragma unroll
            for (int j = 0; j < 8; ++j) {
                unsigned short hh = f2bf(f[j]);
                h[j] = (short)hh;
                l[j] = (short)f2bf(__fsub_rn(f[j], bf2f(hh)));
            }
            bhi[ds] = h; blo[ds] = l;
        }
    }

    // phase 2: k-loop — A-frags direct from L2, 2-term split, no barriers
    float b1v = FLT_MAX, b2v = FLT_MAX;
    int   b1i = 0;
    {
        const int g = lane >> 4;
        const unsigned char* wlp = Wsp + lane * 16;   // per-lane base
        for (int kt = 0; kt < NT; ++kt) {
            const unsigned char* base = wlp + (size_t)kt * TILEB;
            f32x4 acc0 = {0,0,0,0}, acc1 = {0,0,0,0};
            #pragma unroll
            for (int ds = 0; ds < DS; ++ds) {
                bf16x8 ahi = *(const bf16x8*)(base + ds * 1024);
                acc0 = __builtin_amdgcn_mfma_f32_16x16x32_bf16(ahi, bhi[ds], acc0, 0, 0, 0);
                acc1 = __builtin_amdgcn_mfma_f32_16x16x32_bf16(ahi, blo[ds], acc1, 0, 0, 0);
            }
            const int kb = kt * 16 + g * 4;
            #pragma unroll
            for (int r = 0; r < 4; ++r) {              // k-ascending, strict <
                float s = fmaf(-2.f, __fadd_rn(acc0[r], acc1[r]), w2[kb + r]);
                if (s < b1v)      { b2v = b1v; b1v = s; b1i = kb + r; }
                else if (s < b2v) { b2v = s; }
            }
        }
    }

    // phase 3: merge top-2 across code groups; flag; loss from screen d_min
    {
        float v1 = b1v, v2 = b2v; int i1 = b1i;
        #pragma unroll
        for (int m = 16; m < 64; m <<= 1) {
            float o1 = __shfl_xor(v1, m, 64);
            float o2 = __shfl_xor(v2, m, 64);
            int   oi = __shfl_xor(i1, m, 64);
            bool better = (o1 < v1) || (o1 == v1 && oi < i1);
            float nb2 = better ? fminf(v1, o2) : fminf(o1, v2);
            if (better) { v1 = o1; i1 = oi; }
            v2 = nb2;
        }
        float ls = 0.f;
        if ((lane >> 4) == 0) {
            idx_s[tw - t0] = i1;
            idx_out[tw] = (float)i1;
            ls = __fadd_rn(x2v, v1);              // d_min (screen-accurate)
            float margin = fmaf(x2v, 2.6e-7f,
                                fmaf(sqrtf(x2v), mc, 4e-6f));
            if (v2 - v1 <= margin) {              // near-tie: exact rescore
                int p = atomicAdd(cnt_m, 1);
                lst_m[p] = tw;
                keys_m[p] = ~0ULL;
            }
        }
        #pragma unroll
        for (int off = 32; off > 0; off >>= 1) ls += __shfl_down(ls, off, 64);
        if (lane == 0) atomicAdd(P.loss, ls * inv_nd);
    }
    __syncthreads();

    // phase 4: gather q = W[idx] (pure gather+write)
    for (int i = tid; i < 64 * (D / 4); i += 256) {
        int d4 = i % (D / 4);
        int t  = i / (D / 4);
        int k  = idx_s[t];
        const float4 w = *(const float4*)(W + (size_t)k * D + d4 * 4);
        *(float4*)(q_out + (size_t)(t0 + t) * D + d4 * 4) = w;
    }
}

__global__ __launch_bounds__(256) void vq_mega(AllPtrs P) {
    __shared__ int idx_s[64];
    const int bid = blockIdx.x;
    if (bid < 512)       vq_body<256, 512, 0>(P, bid,        idx_s);
    else if (bid < 1024) vq_body<128, 256, 1>(P, bid - 512,  idx_s);
    else if (bid < 1536) vq_body<64,  128, 2>(P, bid - 1024, idx_s);
    else if (bid < 2048) vq_body<128, 256, 3>(P, bid - 1536, idx_s);
    else                 vq_body<64,  128, 4>(P, bid - 2048, idx_s);
}

// ---- cleanup stage 1: (token, 16-code chunk) tasks, atomicMin keys ---------
template <int D, int K, int M>
__device__ void score_body(const AllPtrs& P, int sbid, int sblk)
{
    constexpr int NCH = K / 16;
    constexpr int EPL = D / 16;
    const float* X  = P.X[M];
    const float* W  = P.W[M];
    const float* w2 = P.w2[M];
    const float* x2 = P.x2[M];
    const int* list = P.lst + M * NTOK;
    unsigned long long* keys = P.keys + M * NTOK;
    const int n     = P.cnt[M];
    const int total = n * NCH;
    const int tid = threadIdx.x;
    const int cg  = tid >> 4;
    const int sub = tid & 15;

    for (int task = sbid; task < total; task += sblk) {
        const int e  = task / NCH;
        const int ch = task % NCH;
        const int t  = list[e];
        const int k  = ch * 16 + cg;
        const float* xp = X + (size_t)t * D + sub * EPL;
        const float* wp = W + (size_t)k * D + sub * EPL;
        double a = 0.0;
        #pragma unroll
        for (int j = 0; j < EPL / 4; ++j) {
            const float4 xv = *(const float4*)(xp + j * 4);
            const float4 wv = *(const float4*)(wp + j * 4);
            a = fma((double)xv.x, (double)wv.x, a);
            a = fma((double)xv.y, (double)wv.y, a);
            a = fma((double)xv.z, (double)wv.z, a);
            a = fma((double)xv.w, (double)wv.w, a);
        }
        a += __shfl_down(a, 8, 16);
        a += __shfl_down(a, 4, 16);
        a += __shfl_down(a, 2, 16);
        a += __shfl_down(a, 1, 16);
        if (sub == 0) {
            const float m = (float)a;
            const float d = __fsub_rn(__fadd_rn(x2[t], w2[k]),
                                      __fmul_rn(2.0f, m));
            unsigned long long key =
                ((unsigned long long)__float_as_uint(d) << 32) | (unsigned)k;
            atomicMin(&keys[e], key);
        }
    }
}

__global__ __launch_bounds__(256) void score_mega(AllPtrs P) {
    const int bid = blockIdx.x;
    if (bid < 2048)      score_body<256, 512, 0>(P, bid,        2048);
    else if (bid < 2816) score_body<128, 256, 1>(P, bid - 2048, 768);
    else if (bid < 3072) score_body<64,  128, 2>(P, bid - 2816, 256);
    else if (bid < 3840) score_body<128, 256, 3>(P, bid - 3072, 768);
    else                 score_body<64,  128, 4>(P, bid - 3840, 256);
}

// ---- cleanup stage 2: patch idx / q row / loss for changed tokens ----------
template <int D, int M>
__device__ void apply_body(const AllPtrs& P, int sbid, int sblk)
{
    const float* X = P.X[M];
    const float* W = P.W[M];
    float* q_out   = P.q[M];
    float* idx_out = P.idx[M];
    const int* list = P.lst + M * NTOK;
    const unsigned long long* keys = P.keys + M * NTOK;
    const float inv_nd = 1.0f / (32768.0f * (float)D);
    const int n   = P.cnt[M];
    const int tid = threadIdx.x;

    for (int e = sbid; e < n; e += sblk) {
        const int t    = list[e];
        const int bk   = (int)(unsigned)(keys[e] & 0xFFFFFFFFull);
        const int oldk = (int)idx_out[t];   // all threads read BEFORE write
        __syncthreads();
        if (bk == oldk) continue;           // uniform across block
        if (tid == 0) idx_out[t] = (float)bk;
        const float* xr = X + (size_t)t * D;
        const float* wn = W + (size_t)bk * D;
        const float* wo = W + (size_t)oldk * D;
        float dl = 0.f;
        for (int d = tid; d < D; d += 256) {
            float xv = xr[d], a = wn[d], b = wo[d];
            q_out[(size_t)t * D + d] = a;
            float da = a - xv, db = b - xv;
            dl += da * da - db * db;
        }
        #pragma unroll
        for (int off = 32; off; off >>= 1) dl += __shfl_down(dl, off, 64);
        if ((tid & 63) == 0 && dl != 0.f) atomicAdd(P.loss, dl * inv_nd);
    }
}

__global__ __launch_bounds__(256) void apply_mega(AllPtrs P) {
    const int bid = blockIdx.x;
    if (bid < 256)       apply_body<256, 0>(P, bid,       256);
    else if (bid < 512)  apply_body<128, 1>(P, bid - 256, 256);
    else if (bid < 768)  apply_body<64,  2>(P, bid - 512, 256);
    else if (bid < 1024) apply_body<128, 3>(P, bid - 768, 256);
    else                 apply_body<64,  4>(P, bid - 1024, 256);
}

extern "C" void kernel_launch(void* const* d_in, const int* in_sizes, int n_in,
                              void* d_out, int out_size, void* d_ws, size_t ws_size,
                              hipStream_t stream)
{
    float* out = (float*)d_out;
    unsigned char* wsb = (unsigned char*)d_ws;
    float* w2b = (float*)(wsb + WSB_W2);

    AllPtrs P;
    P.X[0] = (const float*)d_in[0]; P.W[0] = (const float*)d_in[1];
    P.X[1] = (const float*)d_in[2]; P.W[1] = (const float*)d_in[3];
    P.X[2] = (const float*)d_in[4]; P.W[2] = (const float*)d_in[5];
    P.X[3] = (const float*)d_in[6]; P.W[3] = (const float*)d_in[7];
    P.X[4] = (const float*)d_in[8]; P.W[4] = (const float*)d_in[9];

    P.q[0] = out;            P.q[1] = out + 8388608;  P.q[2] = out + 12582912;
    P.q[3] = out + 14680064; P.q[4] = out + 18874368;
    P.idx[0] = out + 20971520; P.idx[1] = out + 21004288;
    P.idx[2] = out + 21037056; P.idx[3] = out + 21069824;
    P.idx[4] = out + 21102592;
    P.loss = out + 21135360;

    P.w2[0] = w2b;       P.w2[1] = w2b + 512; P.w2[2] = w2b + 768;
    P.w2[3] = w2b + 896; P.w2[4] = w2b + 1152;
    float* x2b = (float*)(wsb + WSB_X2);
    for (int m = 0; m < 5; ++m) P.x2[m] = x2b + m * NTOK;
    P.cnt  = (int*)(wsb + WSB_CNT);
    P.lst  = (int*)(wsb + WSB_LIST);
    P.keys = (unsigned long long*)(wsb + WSB_KEY);
    P.Wsp[0] = wsb + WSB_WSP;            // hi-plane packed: 512*256*2 = 262144
    P.Wsp[1] = P.Wsp[0] + 262144;        // 65536
    P.Wsp[2] = P.Wsp[1] + 65536;         // 16384
    P.Wsp[3] = P.Wsp[2] + 16384;         // 65536
    P.Wsp[4] = P.Wsp[3] + 65536;         // 16384

    prep_mega <<<422,  256, 0, stream>>>(P);
    vq_mega   <<<2560, 256, 0, stream>>>(P);
    score_mega<<<4096, 256, 0, stream>>>(P);
    apply_mega<<<1280, 256, 0, stream>>>(P);
}

// Round 15
// 177.636 us; speedup vs baseline: 2.4597x; 2.4597x over previous
//
#include <hip/hip_runtime.h>
#include <float.h>

#define NTOK 32768  // 16 * 2048 tokens per modality

typedef __attribute__((ext_vector_type(8))) short bf16x8;
typedef __attribute__((ext_vector_type(4))) float f32x4;

// ---- ws byte layout ----
#define WSB_W2    0          // 1280 floats
#define WSB_X2    8192       // 5*NTOK floats
#define WSB_CNT   663808     // 5 ints
#define WSB_LIST  664064     // 5*NTOK ints
#define WSB_WSP   1572864    // dual-plane bf16 tile slabs (852 KB)
#define WSB_KEY   2424832    // 5*NTOK u64 argmin keys

#define GLOAD16(g, l)                                                        \
  __builtin_amdgcn_global_load_lds(                                          \
      (__attribute__((address_space(1))) const void*)(const void*)(g),       \
      (__attribute__((address_space(3))) void*)(void*)(l), 16, 0, 0)

struct AllPtrs {
    const float* X[5];
    const float* W[5];
    unsigned char* Wsp[5];
    float* w2[5];
    float* q[5];
    float* idx[5];
    float* x2[5];
    int* cnt;
    int* lst;                  // + m*NTOK
    unsigned long long* keys;  // + m*NTOK
    float* loss;
};

__device__ __forceinline__ unsigned short f2bf(float f) {
    unsigned u = __float_as_uint(f);
    return (unsigned short)((u + 0x7FFFu + ((u >> 16) & 1u)) >> 16);
}
__device__ __forceinline__ float bf2f(unsigned short h) {
    return __uint_as_float(((unsigned)h) << 16);
}

// ============ numpy pairwise-sum replica (fp32, PW_BLOCKSIZE=128) ===========
__device__ __forceinline__ float pw_sq_block_g(const float* __restrict__ a, int n) {
    float r[8];
    #pragma unroll
    for (int j = 0; j < 8; ++j) r[j] = __fmul_rn(a[j], a[j]);
    for (int i = 8; i < n; i += 8)
        #pragma unroll
        for (int j = 0; j < 8; ++j)
            r[j] = __fadd_rn(r[j], __fmul_rn(a[i + j], a[i + j]));
    return __fadd_rn(__fadd_rn(__fadd_rn(r[0], r[1]), __fadd_rn(r[2], r[3])),
                     __fadd_rn(__fadd_rn(r[4], r[5]), __fadd_rn(r[6], r[7])));
}

template <int D>
__device__ __forceinline__ void w2_body(const float* __restrict__ W,
                                        float* __restrict__ w2, int k, int K) {
    if (k >= K) return;
    const float* row = W + (size_t)k * D;
    float s = (D > 128)
        ? __fadd_rn(pw_sq_block_g(row, 128), pw_sq_block_g(row + 128, D - 128))
        : pw_sq_block_g(row, D);
    w2[k] = s;
}

// ---- pack W as per-tile dual-plane fragment slabs -------------------------
// tile slab = D*64 bytes: hi plane (DS x 1KB) then lo plane at +D*32.
// Within a 1KB frag-step: lane l = (row=l&15 | kg=l>>4), 16B per lane.
template <int D, int K>
__device__ __forceinline__ void wsplit_body(const float* __restrict__ W,
                                            unsigned char* __restrict__ dst, int i) {
    if (i >= K * D / 2) return;
    int k  = i / (D / 2);
    int d2 = i % (D / 2);
    int d  = 2 * d2;
    float2 v = *(const float2*)(W + (size_t)k * D + d);
    unsigned short h0 = f2bf(v.x), h1 = f2bf(v.y);
    unsigned short l0 = f2bf(__fsub_rn(v.x, bf2f(h0)));
    unsigned short l1 = f2bf(__fsub_rn(v.y, bf2f(h1)));
    int tile = k >> 4, row = k & 15;
    int ds = d >> 5, kg = (d >> 3) & 3, e = d & 7;
    int lane = row | (kg << 4);
    size_t base = (size_t)tile * (D * 64) + ds * 1024 + lane * 16 + e * 2;
    *(unsigned int*)(dst + base)          = (unsigned)h0 | ((unsigned)h1 << 16);
    *(unsigned int*)(dst + base + D * 32) = (unsigned)l0 | ((unsigned)l1 << 16);
}

// ---- prep: zero loss/cnt, w2 (np-replica), W packed planes ----------------
__global__ __launch_bounds__(256) void prep_mega(AllPtrs P) {
    const int bid = blockIdx.x, tid = threadIdx.x;
    if (bid == 0 && tid == 0) *P.loss = 0.f;
    if (bid == 0 && tid < 5) P.cnt[tid] = 0;
    if (bid < 6) {
        if (bid < 2)      w2_body<256>(P.W[0], P.w2[0], bid * 256 + tid, 512);
        else if (bid == 2) w2_body<128>(P.W[1], P.w2[1], tid, 256);
        else if (bid == 3) w2_body<64> (P.W[2], P.w2[2], tid, 128);
        else if (bid == 4) w2_body<128>(P.W[3], P.w2[3], tid, 256);
        else               w2_body<64> (P.W[4], P.w2[4], tid, 128);
    } else {
        int b = bid - 6;
        if (b < 256)      wsplit_body<256, 512>(P.W[0], P.Wsp[0], b * 256 + tid);
        else if (b < 320) wsplit_body<128, 256>(P.W[1], P.Wsp[1], (b - 256) * 256 + tid);
        else if (b < 336) wsplit_body<64, 128> (P.W[2], P.Wsp[2], (b - 320) * 256 + tid);
        else if (b < 400) wsplit_body<128, 256>(P.W[3], P.Wsp[3], (b - 336) * 256 + tid);
        else              wsplit_body<64, 128> (P.W[4], P.Wsp[4], (b - 400) * 256 + tid);
    }
}

// ---- numpy-pairwise ||x||^2 replica, wave-cooperative ----------------------
template <int D>
__device__ __forceinline__ float x2_replica(const float* __restrict__ xr, int lane) {
    const int jg = (lane >> 4) & 3;
    constexpr int B1M = (D > 128) ? 16 : (D / 8);
    float2 v = *(const float2*)(xr + 2 * jg);
    float r0 = __fmul_rn(v.x, v.x), r1 = __fmul_rn(v.y, v.y);
    #pragma unroll
    for (int m = 1; m < B1M; ++m) {
        float2 u = *(const float2*)(xr + 8 * m + 2 * jg);
        r0 = __fadd_rn(r0, __fmul_rn(u.x, u.x));
        r1 = __fadd_rn(r1, __fmul_rn(u.y, u.y));
    }
    float p = __fadd_rn(r0, r1);
    p = __fadd_rn(p, __shfl_xor(p, 16, 64));
    p = __fadd_rn(p, __shfl_xor(p, 32, 64));
    if (D > 128) {
        float2 w0 = *(const float2*)(xr + 128 + 2 * jg);
        float s0 = __fmul_rn(w0.x, w0.x), s1 = __fmul_rn(w0.y, w0.y);
        #pragma unroll
        for (int m = 1; m < 16; ++m) {
            float2 u = *(const float2*)(xr + 128 + 8 * m + 2 * jg);
            s0 = __fadd_rn(s0, __fmul_rn(u.x, u.x));
            s1 = __fadd_rn(s1, __fmul_rn(u.y, u.y));
        }
        float q2 = __fadd_rn(s0, s1);
        q2 = __fadd_rn(q2, __shfl_xor(q2, 16, 64));
        q2 = __fadd_rn(q2, __shfl_xor(q2, 32, 64));
        p = __fadd_rn(p, q2);
    }
    return p;
}

// ---- MFMA screen body: 512 thr, 128 tok, single-buffer superstages ---------
// CH = k-tiles per stage. Hand: 8 stages x 64KB; ori/nmf: whole W once.
template <int D, int K, int CH, int M>
__device__ void vq_body(const AllPtrs& P, int bid, unsigned char* lds,
                        int* idx_s, float* lred)
{
    constexpr int DS   = D / 32;          // frag-steps per tile
    constexpr int NST  = (K / 16) / CH;   // stages
    constexpr int SB   = CH * D * 64;     // bytes per stage
    constexpr int ITER = SB / 8192;       // GLOAD16 rounds (512 thr)
    const float inv_nd = 1.0f / (32768.0f * (float)D);

    const float* X   = P.X[M];
    const float* W   = P.W[M];
    const unsigned char* Wsp = P.Wsp[M];
    const float* w2  = P.w2[M];
    float* q_out     = P.q[M];
    float* idx_out   = P.idx[M];
    float* x2_save   = P.x2[M];
    int*   cnt_m     = P.cnt + M;
    int*   lst_m     = P.lst + M * NTOK;
    unsigned long long* keys_m = P.keys + M * NTOK;

    const int tid  = threadIdx.x;
    const int lane = tid & 63;
    const int wv   = tid >> 6;            // 0..7
    const int t0   = bid * 128;
    const int tw   = t0 + wv * 16 + (lane & 15);

    // phase 0: np-replica ||x||^2
    const float x2v = x2_replica<D>(X + (size_t)tw * D, lane);
    if ((lane >> 4) == 0) x2_save[tw] = x2v;

    // phase 1: X B-fragments (bf16 hi/lo)
    bf16x8 bhi[DS], blo[DS];
    {
        const float* xr = X + (size_t)tw * D + ((lane >> 4) & 3) * 8;
        #pragma unroll
        for (int ds = 0; ds < DS; ++ds) {
            float4 a = *(const float4*)(xr + ds * 32);
            float4 b = *(const float4*)(xr + ds * 32 + 4);
            float f[8] = {a.x, a.y, a.z, a.w, b.x, b.y, b.z, b.w};
            bf16x8 h, l;
            #pragma unroll
            for (int j = 0; j < 8; ++j) {
                unsigned short hh = f2bf(f[j]);
                h[j] = (short)hh;
                l[j] = (short)f2bf(__fsub_rn(f[j], bf2f(hh)));
            }
            bhi[ds] = h; blo[ds] = l;
        }
    }

    // phase 2: superstaged k-loop, 3-term split, 3 independent MFMA chains
    float b1v = FLT_MAX, b2v = FLT_MAX;
    int   b1i = 0;
    {
        const int g = lane >> 4;
        for (int st = 0; st < NST; ++st) {
            __syncthreads();              // prior stage's reads complete
            const unsigned char* src = Wsp + (size_t)st * SB;
            #pragma unroll
            for (int s = 0; s < ITER; ++s)
                GLOAD16(src + tid * 16 + s * 8192, lds + tid * 16 + s * 8192);
            __syncthreads();              // stage resident
            #pragma unroll
            for (int j = 0; j < CH; ++j) {
                const unsigned char* base = lds + j * (D * 64) + lane * 16;
                f32x4 a0 = {0,0,0,0}, a1 = {0,0,0,0}, a2 = {0,0,0,0};
                #pragma unroll
                for (int ds = 0; ds < DS; ++ds) {
                    bf16x8 ahi = *(const bf16x8*)(base + ds * 1024);
                    bf16x8 alo = *(const bf16x8*)(base + D * 32 + ds * 1024);
                    a0 = __builtin_amdgcn_mfma_f32_16x16x32_bf16(ahi, bhi[ds], a0, 0, 0, 0);
                    a1 = __builtin_amdgcn_mfma_f32_16x16x32_bf16(ahi, blo[ds], a1, 0, 0, 0);
                    a2 = __builtin_amdgcn_mfma_f32_16x16x32_bf16(alo, bhi[ds], a2, 0, 0, 0);
                }
                const int kb = (st * CH + j) * 16 + g * 4;
                #pragma unroll
                for (int r = 0; r < 4; ++r) {          // k-ascending, strict <
                    float dot = __fadd_rn(__fadd_rn(a0[r], a1[r]), a2[r]);
                    float s = fmaf(-2.f, dot, w2[kb + r]);
                    if (s < b1v)      { b2v = b1v; b1v = s; b1i = kb + r; }
                    else if (s < b2v) { b2v = s; }
                }
            }
        }
    }

    // phase 3: merge top-2 across code groups; flag; loss from screen d_min
    {
        float v1 = b1v, v2 = b2v; int i1 = b1i;
        #pragma unroll
        for (int m = 16; m < 64; m <<= 1) {
            float o1 = __shfl_xor(v1, m, 64);
            float o2 = __shfl_xor(v2, m, 64);
            int   oi = __shfl_xor(i1, m, 64);
            bool better = (o1 < v1) || (o1 == v1 && oi < i1);
            float nb2 = better ? fminf(v1, o2) : fminf(o1, v2);
            if (better) { v1 = o1; i1 = oi; }
            v2 = nb2;
        }
        float ls = 0.f;
        if ((lane >> 4) == 0) {
            idx_s[tw - t0] = i1;
            idx_out[tw] = (float)i1;
            ls = __fadd_rn(x2v, v1);              // d_min (screen-accurate)
            float margin = fmaf(x2v, 2.6e-7f, 4e-6f);
            if (v2 - v1 <= margin) {              // near-tie: exact rescore
                int p = atomicAdd(cnt_m, 1);
                lst_m[p] = tw;
                keys_m[p] = ~0ULL;
            }
        }
        #pragma unroll
        for (int off = 32; off > 0; off >>= 1) ls += __shfl_down(ls, off, 64);
        if (lane == 0) lred[wv] = ls;
    }
    __syncthreads();
    if (tid == 0) {
        float tot = 0.f;
        #pragma unroll
        for (int r = 0; r < 8; ++r) tot += lred[r];
        atomicAdd(P.loss, tot * inv_nd);
    }

    // phase 4: gather q = W[idx] (pure gather+write; no X re-read)
    for (int i = tid; i < 128 * (D / 4); i += 512) {
        int d4 = i % (D / 4);
        int t  = i / (D / 4);
        int k  = idx_s[t];
        const float4 w = *(const float4*)(W + (size_t)k * D + d4 * 4);
        *(float4*)(q_out + (size_t)(t0 + t) * D + d4 * 4) = w;
    }
}

__global__ __launch_bounds__(512) void vq_mega(AllPtrs P) {
    __shared__ __align__(16) unsigned char lds[65536];
    __shared__ int   idx_s[128];
    __shared__ float lred[8];
    const int bid = blockIdx.x;
    if (bid < 256)       vq_body<256, 512, 4, 0>(P, bid,        lds, idx_s, lred);
    else if (bid < 512)  vq_body<128, 256, 8, 1>(P, bid - 256,  lds, idx_s, lred);
    else if (bid < 768)  vq_body<128, 256, 8, 3>(P, bid - 512,  lds, idx_s, lred);
    else if (bid < 1024) vq_body<64,  128, 8, 2>(P, bid - 768,  lds, idx_s, lred);
    else                 vq_body<64,  128, 8, 4>(P, bid - 1024, lds, idx_s, lred);
}

// ---- cleanup stage 1: (token, 16-code chunk) tasks, atomicMin keys ---------
template <int D, int K, int M>
__device__ void score_body(const AllPtrs& P, int sbid, int sblk)
{
    constexpr int NCH = K / 16;
    constexpr int EPL = D / 16;
    const float* X  = P.X[M];
    const float* W  = P.W[M];
    const float* w2 = P.w2[M];
    const float* x2 = P.x2[M];
    const int* list = P.lst + M * NTOK;
    unsigned long long* keys = P.keys + M * NTOK;
    const int n     = P.cnt[M];
    const int total = n * NCH;
    const int tid = threadIdx.x;
    const int cg  = tid >> 4;
    const int sub = tid & 15;

    for (int task = sbid; task < total; task += sblk) {
        const int e  = task / NCH;
        const int ch = task % NCH;
        const int t  = list[e];
        const int k  = ch * 16 + cg;
        const float* xp = X + (size_t)t * D + sub * EPL;
        const float* wp = W + (size_t)k * D + sub * EPL;
        double a = 0.0;
        #pragma unroll
        for (int j = 0; j < EPL / 4; ++j) {
            const float4 xv = *(const float4*)(xp + j * 4);
            const float4 wv = *(const float4*)(wp + j * 4);
            a = fma((double)xv.x, (double)wv.x, a);
            a = fma((double)xv.y, (double)wv.y, a);
            a = fma((double)xv.z, (double)wv.z, a);
            a = fma((double)xv.w, (double)wv.w, a);
        }
        a += __shfl_down(a, 8, 16);
        a += __shfl_down(a, 4, 16);
        a += __shfl_down(a, 2, 16);
        a += __shfl_down(a, 1, 16);
        if (sub == 0) {
            const float m = (float)a;
            const float d = __fsub_rn(__fadd_rn(x2[t], w2[k]),
                                      __fmul_rn(2.0f, m));
            unsigned long long key =
                ((unsigned long long)__float_as_uint(d) << 32) | (unsigned)k;
            atomicMin(&keys[e], key);
        }
    }
}

__global__ __launch_bounds__(256) void score_mega(AllPtrs P) {
    const int bid = blockIdx.x;
    if (bid < 2048)      score_body<256, 512, 0>(P, bid,        2048);
    else if (bid < 2816) score_body<128, 256, 1>(P, bid - 2048, 768);
    else if (bid < 3072) score_body<64,  128, 2>(P, bid - 2816, 256);
    else if (bid < 3840) score_body<128, 256, 3>(P, bid - 3072, 768);
    else                 score_body<64,  128, 4>(P, bid - 3840, 256);
}

// ---- cleanup stage 2: patch idx / q row / loss for changed tokens ----------
template <int D, int M>
__device__ void apply_body(const AllPtrs& P, int sbid, int sblk)
{
    const float* X = P.X[M];
    const float* W = P.W[M];
    float* q_out   = P.q[M];
    float* idx_out = P.idx[M];
    const int* list = P.lst + M * NTOK;
    const unsigned long long* keys = P.keys + M * NTOK;
    const float inv_nd = 1.0f / (32768.0f * (float)D);
    const int n   = P.cnt[M];
    const int tid = threadIdx.x;

    for (int e = sbid; e < n; e += sblk) {
        const int t    = list[e];
        const int bk   = (int)(unsigned)(keys[e] & 0xFFFFFFFFull);
        const int oldk = (int)idx_out[t];   // all threads read BEFORE write
        __syncthreads();
        if (bk == oldk) continue;           // uniform across block
        if (tid == 0) idx_out[t] = (float)bk;
        const float* xr = X + (size_t)t * D;
        const float* wn = W + (size_t)bk * D;
        const float* wo = W + (size_t)oldk * D;
        float dl = 0.f;
        for (int d = tid; d < D; d += 256) {
            float xv = xr[d], a = wn[d], b = wo[d];
            q_out[(size_t)t * D + d] = a;
            float da = a - xv, db = b - xv;
            dl += da * da - db * db;
        }
        #pragma unroll
        for (int off = 32; off; off >>= 1) dl += __shfl_down(dl, off, 64);
        if ((tid & 63) == 0 && dl != 0.f) atomicAdd(P.loss, dl * inv_nd);
    }
}

__global__ __launch_bounds__(256) void apply_mega(AllPtrs P) {
    const int bid = blockIdx.x;
    if (bid < 256)       apply_body<256, 0>(P, bid,       256);
    else if (bid < 512)  apply_body<128, 1>(P, bid - 256, 256);
    else if (bid < 768)  apply_body<64,  2>(P, bid - 512, 256);
    else if (bid < 1024) apply_body<128, 3>(P, bid - 768, 256);
    else                 apply_body<64,  4>(P, bid - 1024, 256);
}

extern "C" void kernel_launch(void* const* d_in, const int* in_sizes, int n_in,
                              void* d_out, int out_size, void* d_ws, size_t ws_size,
                              hipStream_t stream)
{
    float* out = (float*)d_out;
    unsigned char* wsb = (unsigned char*)d_ws;
    float* w2b = (float*)(wsb + WSB_W2);

    AllPtrs P;
    P.X[0] = (const float*)d_in[0]; P.W[0] = (const float*)d_in[1];
    P.X[1] = (const float*)d_in[2]; P.W[1] = (const float*)d_in[3];
    P.X[2] = (const float*)d_in[4]; P.W[2] = (const float*)d_in[5];
    P.X[3] = (const float*)d_in[6]; P.W[3] = (const float*)d_in[7];
    P.X[4] = (const float*)d_in[8]; P.W[4] = (const float*)d_in[9];

    P.q[0] = out;            P.q[1] = out + 8388608;  P.q[2] = out + 12582912;
    P.q[3] = out + 14680064; P.q[4] = out + 18874368;
    P.idx[0] = out + 20971520; P.idx[1] = out + 21004288;
    P.idx[2] = out + 21037056; P.idx[3] = out + 21069824;
    P.idx[4] = out + 21102592;
    P.loss = out + 21135360;

    P.w2[0] = w2b;       P.w2[1] = w2b + 512; P.w2[2] = w2b + 768;
    P.w2[3] = w2b + 896; P.w2[4] = w2b + 1152;
    float* x2b = (float*)(wsb + WSB_X2);
    for (int m = 0; m < 5; ++m) P.x2[m] = x2b + m * NTOK;
    P.cnt  = (int*)(wsb + WSB_CNT);
    P.lst  = (int*)(wsb + WSB_LIST);
    P.keys = (unsigned long long*)(wsb + WSB_KEY);
    P.Wsp[0] = wsb + WSB_WSP;            // dual-plane: 4*K*D bytes each
    P.Wsp[1] = P.Wsp[0] + 524288;        // 131072
    P.Wsp[2] = P.Wsp[1] + 131072;        // 32768
    P.Wsp[3] = P.Wsp[2] + 32768;         // 131072
    P.Wsp[4] = P.Wsp[3] + 131072;        // 32768

    prep_mega <<<422,  256, 0, stream>>>(P);
    vq_mega   <<<1280, 512, 0, stream>>>(P);
    score_mega<<<4096, 256, 0, stream>>>(P);
    apply_mega<<<1280, 256, 0, stream>>>(P);
}